// Round 7
// baseline (579.835 us; speedup 1.0000x reference)
//
#include <hip/hip_runtime.h>
#include <hip/hip_bf16.h>
#include <stdint.h>

#define HIDDEN 256
#define NMEM   1024
#define NTILES 32
#define LOG2E  1.44269504088896340736f

typedef __attribute__((ext_vector_type(8)))  short bf16x8;
typedef __attribute__((ext_vector_type(16))) float f32x16;
typedef unsigned short ushort_t;
typedef unsigned int   uint_t;

__device__ __forceinline__ ushort_t f2bf(float f) {
  uint_t u = __builtin_bit_cast(uint_t, f);
  u += 0x7FFFu + ((u >> 16) & 1u);   // RNE (no NaN inputs here)
  return (ushort_t)(u >> 16);
}

__device__ __forceinline__ void gload_lds16(const void* g, void* l) {
  __builtin_amdgcn_global_load_lds(
      (const __attribute__((address_space(1))) uint_t*)g,
      (__attribute__((address_space(3))) uint_t*)l, 16, 0, 0);
}

// ---------------- prep: normalize memories; emit LDS-image layouts -------------
// 32 tiles of 32 mems each (16 KB m_hat + 16 KB V^T per tile):
// wsm: tile t: [32 mem][32 chunks of 8 bf16]; chunk c stored at c^(mem&7)
// wsv: tile t: [256 d][4 chunks of 8 mems];   chunk c stored at c^((d>>1)&3)
__global__ void prep_kernel(const float* __restrict__ mem,
                            ushort_t* __restrict__ wsm,
                            ushort_t* __restrict__ wsv) {
  const int m = blockIdx.x;
  const int k = threadIdx.x;
  float v = mem[m * HIDDEN + k];
  float ss = v * v;
  #pragma unroll
  for (int off = 1; off < 64; off <<= 1) ss += __shfl_xor(ss, off);
  __shared__ float red[4];
  if ((k & 63) == 0) red[k >> 6] = ss;
  __syncthreads();
  const float tot = red[0] + red[1] + red[2] + red[3];
  const float inv = 1.0f / fmaxf(sqrtf(tot), 1e-12f);
  const ushort_t hn = f2bf(v * inv);
  const ushort_t hv = f2bf(v);
  const int t = m >> 5, mr = m & 31;
  wsm[t * 8192 + mr * 256 + (((k >> 3) ^ (mr & 7)) << 3) + (k & 7)] = hn;
  wsv[t * 8192 + k * 32  + (((mr >> 3) ^ ((k >> 1) & 3)) << 3) + (mr & 7)] = hv;
}

// ---------------- main: fused cosine-softmax memory read -----------------------
// 8 waves x 32 rows; 32 KV tiles of 32 mems, TRIPLE-buffered in 96KB LDS.
// Software-pipelined: loop body = stage(t+1) | QK(t) | PV(t-1) | pack(t),
// so PV's MFMAs overlap QK's ds_reads and pack's VALU has no in-tile consumer.
__global__ __launch_bounds__(512, 2) void mem_kernel(
    const float* __restrict__ x, const ushort_t* __restrict__ wsm,
    const ushort_t* __restrict__ wsv, float* __restrict__ out) {
  __shared__ __align__(16) char lds[98304];
  const int tid  = threadIdx.x;
  const int lane = tid & 63;
  const int wave = tid >> 6;
  const int col  = lane & 31;           // QK: x-row | PV: d-col key
  const int hi   = lane >> 5;
  const int row0 = blockIdx.x * 256 + wave * 32;
  const char* gm = (const char*)wsm;
  const char* gv = (const char*)wsv;

  auto stage = [&](int t, int b) {      // 32 KB tile-pair -> LDS buf b
    const int bb = b * 32768;
    const int go = t * 16384;
    #pragma unroll
    for (int r = 0; r < 2; ++r) {
      const int o = wave * 2048 + r * 1024;
      gload_lds16(gm + go + o + lane * 16, lds + bb + o);
      gload_lds16(gv + go + o + lane * 16, lds + bb + 16384 + o);
    }
  };

  stage(0, 0);                          // overlap with x prologue

  // ---- x rows: on-the-fly bf16 convert (UNSCALED), f32 norm accumulation
  bf16x8 xb[16];
  float ss = 0.f;
  const float* xr = x + (size_t)(row0 + col) * HIDDEN + hi * 8;
  #pragma unroll
  for (int ks = 0; ks < 16; ++ks) {
    float4 a = *(const float4*)(xr + ks * 16);
    float4 b = *(const float4*)(xr + ks * 16 + 4);
    ss += a.x*a.x + a.y*a.y + a.z*a.z + a.w*a.w
        + b.x*b.x + b.y*b.y + b.z*b.z + b.w*b.w;
    xb[ks][0] = (short)f2bf(a.x); xb[ks][1] = (short)f2bf(a.y);
    xb[ks][2] = (short)f2bf(a.z); xb[ks][3] = (short)f2bf(a.w);
    xb[ks][4] = (short)f2bf(b.x); xb[ks][5] = (short)f2bf(b.y);
    xb[ks][6] = (short)f2bf(b.z); xb[ks][7] = (short)f2bf(b.w);
  }
  ss += __shfl_xor(ss, 32);             // (col,0)+(col,1) = full row
  const float myscale = (2.0f * LOG2E) / fmaxf(sqrtf(ss), 1e-12f);

  const f32x16 zz = {0.f,0.f,0.f,0.f, 0.f,0.f,0.f,0.f,
                     0.f,0.f,0.f,0.f, 0.f,0.f,0.f,0.f};
  f32x16 o8[8];
  #pragma unroll
  for (int i = 0; i < 8; ++i) o8[i] = zz;
  float den0 = 0.f, den1 = 0.f;
  bf16x8 pa[2];                         // pipelined P-frags (tile t-1)

  const int ck7 = col & 7;              // QK chunk-swizzle key
  const int ck3 = (col >> 1) & 3;       // PV chunk-swizzle key

  // ---- QK of tile in buf qb -> s0,s1 (layout verbatim from verified kernel)
  auto qk = [&](int qb, f32x16& s0, f32x16& s1) {
    const char* ab = lds + qb * 32768 + col * 512;
    s0 = zz; s1 = zz;
    #pragma unroll
    for (int ks2 = 0; ks2 < 8; ++ks2) {
      bf16x8 a0 = *(const bf16x8*)(ab + (((4*ks2 + hi)     ^ ck7) << 4));
      bf16x8 a1 = *(const bf16x8*)(ab + (((4*ks2 + 2 + hi) ^ ck7) << 4));
      s0 = __builtin_amdgcn_mfma_f32_32x32x16_bf16(a0, xb[2*ks2],   s0, 0,0,0);
      s1 = __builtin_amdgcn_mfma_f32_32x32x16_bf16(a1, xb[2*ks2+1], s1, 0,0,0);
    }
  };

  // ---- exp2 + cvt_pk + permlane -> pa (straight-line, unconditional)
  auto pack = [&](const f32x16& s0, const f32x16& s1) {
    #pragma unroll
    for (int ks = 0; ks < 2; ++ks) {
      const int b0 = ks * 8;
      const float e0 = exp2f((s0[b0+0] + s1[b0+0]) * myscale);
      const float e1 = exp2f((s0[b0+1] + s1[b0+1]) * myscale);
      const float e2 = exp2f((s0[b0+2] + s1[b0+2]) * myscale);
      const float e3 = exp2f((s0[b0+3] + s1[b0+3]) * myscale);
      const float e4 = exp2f((s0[b0+4] + s1[b0+4]) * myscale);
      const float e5 = exp2f((s0[b0+5] + s1[b0+5]) * myscale);
      const float e6 = exp2f((s0[b0+6] + s1[b0+6]) * myscale);
      const float e7 = exp2f((s0[b0+7] + s1[b0+7]) * myscale);
      den0 += (e0 + e1) + (e2 + e3);
      den1 += (e4 + e5) + (e6 + e7);
      uint_t w0, w1, w2, w3;
      asm("v_cvt_pk_bf16_f32 %0, %1, %2" : "=v"(w0) : "v"(e0), "v"(e1));
      asm("v_cvt_pk_bf16_f32 %0, %1, %2" : "=v"(w1) : "v"(e2), "v"(e3));
      asm("v_cvt_pk_bf16_f32 %0, %1, %2" : "=v"(w2) : "v"(e4), "v"(e5));
      asm("v_cvt_pk_bf16_f32 %0, %1, %2" : "=v"(w3) : "v"(e6), "v"(e7));
      asm("v_permlane32_swap_b32 %0, %1" : "+v"(w0), "+v"(w2));
      asm("v_permlane32_swap_b32 %0, %1" : "+v"(w1), "+v"(w3));
      uint4 u = {w0, w1, w2, w3};
      pa[ks] = __builtin_bit_cast(bf16x8, u);
    }
  };

  // ---- PV of tile in buf pb using current pa -> o8
  auto pv = [&](int pb) {
    const char* vrb = lds + pb * 32768 + 16384 + col * 64;
    #pragma unroll
    for (int ks = 0; ks < 2; ++ks) {
      const int cc = ((2*ks + hi) ^ ck3) << 4;
      #pragma unroll
      for (int d0 = 0; d0 < 8; ++d0) {
        bf16x8 vf = *(const bf16x8*)(vrb + d0 * 2048 + cc);
        o8[d0] = __builtin_amdgcn_mfma_f32_32x32x16_bf16(pa[ks], vf, o8[d0], 0,0,0);
      }
    }
  };

  // pipelined iteration: stage(t+1) | QK(t) | PV(t-1) | pack(t) | barrier
  auto iter = [&](int t, int qb, int pb, int sb, bool do_stage) {
    if (do_stage) stage(t + 1, sb);
    __builtin_amdgcn_s_setprio(1);
    f32x16 s0, s1;
    qk(qb, s0, s1);
    pv(pb);                             // consumes OLD pa (tile t-1)
    pack(s0, s1);                       // overwrites pa (tile t)
    __builtin_amdgcn_s_setprio(0);
    __syncthreads();
  };

  __syncthreads();                      // tile 0 staged

  // t = 0: no PV yet
  stage(1, 1);
  __builtin_amdgcn_s_setprio(1);
  { f32x16 s0, s1; qk(0, s0, s1); pack(s0, s1); }
  __builtin_amdgcn_s_setprio(0);
  __syncthreads();

  // t = 1..30, buffer pattern period 3: (q,p,s) = (t%3, (t-1)%3, (t+1)%3)
  #pragma unroll 1
  for (int tb = 1; tb < 31; tb += 3) {
    iter(tb,     1, 0, 2, true);
    iter(tb + 1, 2, 1, 0, true);
    iter(tb + 2, 0, 2, 1, true);
  }
  iter(31, 1, 0, 0, false);             // t = 31, no stage
  pv(1);                                // PV of tile 31 (buf 31%3 = 1)

  // ---- denominators: lane covers hi-half mems of x-row col
  float den = den0 + den1;
  den += __shfl_xor(den, 32);
  const float rden = 1.0f / den;
  float rdv[16];
  #pragma unroll
  for (int r = 0; r < 16; ++r)
    rdv[r] = __shfl(rden, (r & 3) + 8 * (r >> 2) + 4 * hi);

  // ---- normalize + store: row = crow(r,hi), d = d0*32+col (128B segments)
  float* op = out + (size_t)row0 * HIDDEN;
  #pragma unroll
  for (int d0 = 0; d0 < 8; ++d0) {
    #pragma unroll
    for (int r = 0; r < 16; ++r) {
      const int rw = (r & 3) + 8 * (r >> 2) + 4 * hi;
      op[(size_t)rw * HIDDEN + d0 * 32 + col] = o8[d0][r] * rdv[r];
    }
  }
}

extern "C" void kernel_launch(void* const* d_in, const int* in_sizes, int n_in,
                              void* d_out, int out_size, void* d_ws, size_t ws_size,
                              hipStream_t stream) {
  const float* x   = (const float*)d_in[0];
  const float* mem = (const float*)d_in[1];
  float* out = (float*)d_out;
  const int N = in_sizes[0] / HIDDEN;          // 131072

  ushort_t* wsm = (ushort_t*)d_ws;             // 512 KB (m_hat image)
  ushort_t* wsv = wsm + NMEM * HIDDEN;         // 512 KB (V^T image)

  prep_kernel<<<NMEM, HIDDEN, 0, stream>>>(mem, wsm, wsv);
  mem_kernel<<<N / 256, 512, 0, stream>>>(x, wsm, wsv, out);
}

// Round 8
// 371.677 us; speedup vs baseline: 1.5600x; 1.5600x over previous
//
#include <hip/hip_runtime.h>
#include <hip/hip_bf16.h>
#include <stdint.h>

#define HIDDEN 256
#define NMEM   1024
#define NTILES 32
#define LOG2E  1.44269504088896340736f

typedef __attribute__((ext_vector_type(8)))  short bf16x8;
typedef __attribute__((ext_vector_type(16))) float f32x16;
typedef unsigned short ushort_t;
typedef unsigned int   uint_t;

__device__ __forceinline__ ushort_t f2bf(float f) {
  uint_t u = __builtin_bit_cast(uint_t, f);
  u += 0x7FFFu + ((u >> 16) & 1u);   // RNE (no NaN inputs here)
  return (ushort_t)(u >> 16);
}

__device__ __forceinline__ void gload_lds16(const void* g, void* l) {
  __builtin_amdgcn_global_load_lds(
      (const __attribute__((address_space(1))) uint_t*)g,
      (__attribute__((address_space(3))) uint_t*)l, 16, 0, 0);
}

// ---------------- prep: normalize memories; emit LDS-image layouts -------------
// 32 tiles of 32 mems each (16 KB m_hat + 16 KB V^T per tile):
// wsm: tile t: [32 mem][32 chunks of 8 bf16]; chunk c stored at c^(mem&7)
// wsv: tile t: [256 d][4 chunks of 8 mems];   chunk c stored at c^((d>>1)&3)
__global__ void prep_kernel(const float* __restrict__ mem,
                            ushort_t* __restrict__ wsm,
                            ushort_t* __restrict__ wsv) {
  const int m = blockIdx.x;
  const int k = threadIdx.x;
  float v = mem[m * HIDDEN + k];
  float ss = v * v;
  #pragma unroll
  for (int off = 1; off < 64; off <<= 1) ss += __shfl_xor(ss, off);
  __shared__ float red[4];
  if ((k & 63) == 0) red[k >> 6] = ss;
  __syncthreads();
  const float tot = red[0] + red[1] + red[2] + red[3];
  const float inv = 1.0f / fmaxf(sqrtf(tot), 1e-12f);
  const ushort_t hn = f2bf(v * inv);
  const ushort_t hv = f2bf(v);
  const int t = m >> 5, mr = m & 31;
  wsm[t * 8192 + mr * 256 + (((k >> 3) ^ (mr & 7)) << 3) + (k & 7)] = hn;
  wsv[t * 8192 + k * 32  + (((mr >> 3) ^ ((k >> 1) & 3)) << 3) + (mr & 7)] = hv;
}

// ---------------- main: fused cosine-softmax memory read -----------------------
// 4 waves x 32 rows = 128 rows/block; 32 KV tiles of 32 mems, dbuf in 64KB LDS.
// 2 blocks/CU (8 waves, register-capped) -> two independent barrier domains so
// one block's MFMA/LDS phase overlaps the other's VALU phase.
// Per-wave code verbatim from the round-6 kernel (passed, 238.6us, no spill).
__global__ __launch_bounds__(256, 2) void mem_kernel(
    const float* __restrict__ x, const ushort_t* __restrict__ wsm,
    const ushort_t* __restrict__ wsv, float* __restrict__ out) {
  __shared__ __align__(16) char lds[65536];
  const int tid  = threadIdx.x;
  const int lane = tid & 63;
  const int wave = tid >> 6;            // 0..3
  const int col  = lane & 31;           // QK: x-row | PV: d-col key
  const int hi   = lane >> 5;
  const int row0 = blockIdx.x * 128 + wave * 32;
  const char* gm = (const char*)wsm;
  const char* gv = (const char*)wsv;

  auto stage = [&](int t, int buf) {    // 32 KB tile-pair -> LDS, linear dest
    const int bb = buf << 15;
    const int go = t * 16384;
    #pragma unroll
    for (int r = 0; r < 4; ++r) {
      const int o = wave * 4096 + r * 1024;
      gload_lds16(gm + go + o + lane * 16, lds + bb + o);
      gload_lds16(gv + go + o + lane * 16, lds + bb + 16384 + o);
    }
  };

  stage(0, 0);                          // overlap with x prologue

  // ---- x rows: on-the-fly bf16 convert (UNSCALED), f32 norm accumulation.
  // Lane (col,hi) holds B-frag elems k = ks*16 + hi*8 + j  (no f32 staging)
  bf16x8 xb[16];
  float ss = 0.f;
  const float* xr = x + (size_t)(row0 + col) * HIDDEN + hi * 8;
  #pragma unroll
  for (int ks = 0; ks < 16; ++ks) {
    float4 a = *(const float4*)(xr + ks * 16);
    float4 b = *(const float4*)(xr + ks * 16 + 4);
    ss += a.x*a.x + a.y*a.y + a.z*a.z + a.w*a.w
        + b.x*b.x + b.y*b.y + b.z*b.z + b.w*b.w;
    xb[ks][0] = (short)f2bf(a.x); xb[ks][1] = (short)f2bf(a.y);
    xb[ks][2] = (short)f2bf(a.z); xb[ks][3] = (short)f2bf(a.w);
    xb[ks][4] = (short)f2bf(b.x); xb[ks][5] = (short)f2bf(b.y);
    xb[ks][6] = (short)f2bf(b.z); xb[ks][7] = (short)f2bf(b.w);
  }
  ss += __shfl_xor(ss, 32);             // (col,0)+(col,1) = full row
  // logits = 2*cos; fold 2*log2e/||x|| into exp2 argument (lane-local scale)
  const float myscale = (2.0f * LOG2E) / fmaxf(sqrtf(ss), 1e-12f);

  const f32x16 zz = {0.f,0.f,0.f,0.f, 0.f,0.f,0.f,0.f,
                     0.f,0.f,0.f,0.f, 0.f,0.f,0.f,0.f};
  f32x16 o8[8];
  #pragma unroll
  for (int i = 0; i < 8; ++i) o8[i] = zz;
  float den = 0.f;

  const int ck7 = col & 7;              // QK chunk-swizzle key
  const int ck3 = (col >> 1) & 3;       // PV chunk-swizzle key

  __syncthreads();                      // tile 0 landed

  for (int t = 0; t < NTILES; ++t) {
    const int mb = (t & 1) << 15;
    const int vb = mb + 16384;
    if (t < NTILES - 1) stage(t + 1, (t & 1) ^ 1);
    __builtin_amdgcn_s_setprio(1);

    // ---- QK: S[mem][xrow]; A = m_hat row col (LDS), B = x raw bf16 (regs)
    const char* ab = lds + mb + col * 512;
    f32x16 s0 = zz, s1 = zz;            // 2 chains for MFMA ILP
    #pragma unroll
    for (int ks2 = 0; ks2 < 8; ++ks2) {
      bf16x8 a0 = *(const bf16x8*)(ab + (((4*ks2 + hi)     ^ ck7) << 4));
      bf16x8 a1 = *(const bf16x8*)(ab + (((4*ks2 + 2 + hi) ^ ck7) << 4));
      s0 = __builtin_amdgcn_mfma_f32_32x32x16_bf16(a0, xb[2*ks2],   s0, 0,0,0);
      s1 = __builtin_amdgcn_mfma_f32_32x32x16_bf16(a1, xb[2*ks2+1], s1, 0,0,0);
    }

    // ---- p = exp2(s * myscale); lane holds P[xrow=col][mem=crow(r,hi)]
    float p[16];
    #pragma unroll
    for (int r = 0; r < 16; ++r) {
      const float pv = exp2f((s0[r] + s1[r]) * myscale);
      den += pv;
      p[r] = pv;
    }

    // ---- P -> PV A-frags: pack bf16 pairs, permlane32_swap halves (T12)
    bf16x8 pa[2];
    #pragma unroll
    for (int ks = 0; ks < 2; ++ks) {
      const int b0 = ks * 8;
      uint_t w0 = (uint_t)f2bf(p[b0+0]) | ((uint_t)f2bf(p[b0+1]) << 16);
      uint_t w1 = (uint_t)f2bf(p[b0+2]) | ((uint_t)f2bf(p[b0+3]) << 16);
      uint_t w2 = (uint_t)f2bf(p[b0+4]) | ((uint_t)f2bf(p[b0+5]) << 16);
      uint_t w3 = (uint_t)f2bf(p[b0+6]) | ((uint_t)f2bf(p[b0+7]) << 16);
      asm("v_permlane32_swap_b32 %0, %1" : "+v"(w0), "+v"(w2));
      asm("v_permlane32_swap_b32 %0, %1" : "+v"(w1), "+v"(w3));
      uint4 u = {w0, w1, w2, w3};
      pa[ks] = __builtin_bit_cast(bf16x8, u);
    }

    // ---- PV: O += P x V; B-frag = V^T row d (contiguous 8 mems per lane)
    const char* vrb = lds + vb + col * 64;
    #pragma unroll
    for (int ks = 0; ks < 2; ++ks) {
      const int cc = ((2*ks + hi) ^ ck3) << 4;
      #pragma unroll
      for (int d0 = 0; d0 < 8; ++d0) {
        bf16x8 vf = *(const bf16x8*)(vrb + d0 * 2048 + cc);
        o8[d0] = __builtin_amdgcn_mfma_f32_32x32x16_bf16(pa[ks], vf, o8[d0], 0,0,0);
      }
    }
    __builtin_amdgcn_s_setprio(0);
    __syncthreads();                    // stage landed + buffer reads done
  }

  // ---- denominators: lane covers hi-half mems of x-row col
  den += __shfl_xor(den, 32);
  const float rden = 1.0f / den;
  float rdv[16];
  #pragma unroll
  for (int r = 0; r < 16; ++r)
    rdv[r] = __shfl(rden, (r & 3) + 8 * (r >> 2) + 4 * hi);

  // ---- normalize + store: row = crow(r,hi), d = d0*32+col (128B segments)
  float* op = out + (size_t)row0 * HIDDEN;
  #pragma unroll
  for (int d0 = 0; d0 < 8; ++d0) {
    #pragma unroll
    for (int r = 0; r < 16; ++r) {
      const int rw = (r & 3) + 8 * (r >> 2) + 4 * hi;
      op[(size_t)rw * HIDDEN + d0 * 32 + col] = o8[d0][r] * rdv[r];
    }
  }
}

extern "C" void kernel_launch(void* const* d_in, const int* in_sizes, int n_in,
                              void* d_out, int out_size, void* d_ws, size_t ws_size,
                              hipStream_t stream) {
  const float* x   = (const float*)d_in[0];
  const float* mem = (const float*)d_in[1];
  float* out = (float*)d_out;
  const int N = in_sizes[0] / HIDDEN;          // 131072

  ushort_t* wsm = (ushort_t*)d_ws;             // 512 KB (m_hat image)
  ushort_t* wsv = wsm + NMEM * HIDDEN;         // 512 KB (V^T image)

  prep_kernel<<<NMEM, HIDDEN, 0, stream>>>(mem, wsm, wsv);
  mem_kernel<<<N / 128, 256, 0, stream>>>(x, wsm, wsv, out);
}

// Round 11
// 347.177 us; speedup vs baseline: 1.6701x; 1.0706x over previous
//
#include <hip/hip_runtime.h>
#include <hip/hip_bf16.h>
#include <stdint.h>

#define HIDDEN 256
#define NMEM   1024
#define LOG2E  1.44269504088896340736f

typedef __attribute__((ext_vector_type(8)))  short bf16x8;
typedef __attribute__((ext_vector_type(16))) float f32x16;
typedef unsigned short ushort_t;
typedef unsigned int   uint_t;

__device__ __forceinline__ ushort_t f2bf(float f) {
  uint_t u = __builtin_bit_cast(uint_t, f);
  u += 0x7FFFu + ((u >> 16) & 1u);   // RNE (no NaN inputs here)
  return (ushort_t)(u >> 16);
}

__device__ __forceinline__ void gload_lds16(const void* g, void* l) {
  __builtin_amdgcn_global_load_lds(
      (const __attribute__((address_space(1))) uint_t*)g,
      (__attribute__((address_space(3))) uint_t*)l, 16, 0, 0);
}

// ---------------- prep: normalize memories; emit FRAGMENT-ORDER LDS images ----
// Images are laid out so the main kernel's every ds_read_b128 is
// (lane*16 + compile-time immediate): zero address VALU, lane-linear
// (conflict-free), and global_load_lds stages them verbatim (linear dest).
// Per 32-mem tile (16384 B each image):
//  wsm (QK A-frags):  byte = sel*8192 + ks*1024 + hi*512 + mr*16 + j*2
//     where chunk c=k>>3 = 4*ks + 2*sel + hi  (j = k&7)
//  wsv (PV B-frags):  byte = d0*2048 + ks*1024 + hi*512 + col*16 + j*2
//     where d0=d>>5, col=d&31, mem-chunk c2=mr>>3 = 2*ks+hi, j = mr&7
__global__ void prep_kernel(const float* __restrict__ mem,
                            ushort_t* __restrict__ wsm,
                            ushort_t* __restrict__ wsv) {
  const int m = blockIdx.x;
  const int k = threadIdx.x;
  float v = mem[m * HIDDEN + k];
  float ss = v * v;
  #pragma unroll
  for (int off = 1; off < 64; off <<= 1) ss += __shfl_xor(ss, off);
  __shared__ float red[4];
  if ((k & 63) == 0) red[k >> 6] = ss;
  __syncthreads();
  const float tot = red[0] + red[1] + red[2] + red[3];
  const float inv = 1.0f / fmaxf(sqrtf(tot), 1e-12f);
  const ushort_t hn = f2bf(v * inv);
  const ushort_t hv = f2bf(v);
  const int t = m >> 5, mr = m & 31;
  const int c = k >> 3;
  // QK image (ushort index = byte/2)
  wsm[t * 8192 + ((c >> 1) & 1) * 4096 + (c >> 2) * 512 + (c & 1) * 256
      + mr * 8 + (k & 7)] = hn;
  // PV image
  wsv[t * 8192 + (k >> 5) * 1024 + ((mr >> 3) >> 1) * 512 + ((mr >> 3) & 1) * 256
      + (k & 31) * 8 + (mr & 7)] = hv;
}

// ---------------- main: fused cosine-softmax memory read -----------------------
// 4 waves x 32 rows = 128 rows/block; 32 KV tiles of 32 mems, dbuf in 64KB LDS.
// All K-loop ds_reads are (lane*16 + immediate); buffer toggle is folded into
// the 16-bit ds offset by unrolling 2 tiles/iteration (imm 0 / 32768).
__global__ __launch_bounds__(256, 2) void mem_kernel(
    const float* __restrict__ x, const ushort_t* __restrict__ wsm,
    const ushort_t* __restrict__ wsv, float* __restrict__ out) {
  __shared__ __align__(16) char lds[65536];
  const int tid  = threadIdx.x;
  const int lane = tid & 63;
  const int wave = tid >> 6;            // 0..3
  const int col  = lane & 31;
  const int hi   = lane >> 5;
  const int row0 = blockIdx.x * 128 + wave * 32;
  const char* gm = (const char*)wsm;
  const char* gv = (const char*)wsv;

  auto stage = [&](int t, int buf) {    // 32 KB tile-pair -> LDS, linear dest
    const int bb = buf << 15;
    const int go = t * 16384;
    #pragma unroll
    for (int r = 0; r < 4; ++r) {
      const int o = wave * 4096 + r * 1024;
      gload_lds16(gm + go + o + lane * 16, lds + bb + o);
      gload_lds16(gv + go + o + lane * 16, lds + bb + 16384 + o);
    }
  };

  stage(0, 0);                          // overlap with x prologue

  // ---- x rows: on-the-fly bf16 convert (UNSCALED), f32 norm accumulation.
  bf16x8 xb[16];
  float ss = 0.f;
  const float* xr = x + (size_t)(row0 + col) * HIDDEN + hi * 8;
  #pragma unroll
  for (int ks = 0; ks < 16; ++ks) {
    float4 a = *(const float4*)(xr + ks * 16);
    float4 b = *(const float4*)(xr + ks * 16 + 4);
    ss += a.x*a.x + a.y*a.y + a.z*a.z + a.w*a.w
        + b.x*b.x + b.y*b.y + b.z*b.z + b.w*b.w;
    xb[ks][0] = (short)f2bf(a.x); xb[ks][1] = (short)f2bf(a.y);
    xb[ks][2] = (short)f2bf(a.z); xb[ks][3] = (short)f2bf(a.w);
    xb[ks][4] = (short)f2bf(b.x); xb[ks][5] = (short)f2bf(b.y);
    xb[ks][6] = (short)f2bf(b.z); xb[ks][7] = (short)f2bf(b.w);
  }
  ss += __shfl_xor(ss, 32);             // (col,0)+(col,1) = full row
  const float myscale = (2.0f * LOG2E) / fmaxf(sqrtf(ss), 1e-12f);

  const f32x16 zz = {0.f,0.f,0.f,0.f, 0.f,0.f,0.f,0.f,
                     0.f,0.f,0.f,0.f, 0.f,0.f,0.f,0.f};
  f32x16 o8[8];
  #pragma unroll
  for (int i = 0; i < 8; ++i) o8[i] = zz;
  float den = 0.f;

  const char* ldsb = lds + lane * 16;   // the ONE address register

  __syncthreads();                      // tile 0 landed

  // tile body: IMM = buffer byte base (0 / 32768), folded into ds offsets
#define TILE_BODY(IMM)                                                        \
  do {                                                                        \
    __builtin_amdgcn_s_setprio(1);                                            \
    f32x16 s0 = zz, s1 = zz;                                                  \
    _Pragma("unroll")                                                         \
    for (int ks2 = 0; ks2 < 8; ++ks2) {                                       \
      bf16x8 a0 = *(const bf16x8*)(ldsb + (IMM) + ks2 * 1024);                \
      bf16x8 a1 = *(const bf16x8*)(ldsb + (IMM) + 8192 + ks2 * 1024);         \
      s0 = __builtin_amdgcn_mfma_f32_32x32x16_bf16(a0, xb[2*ks2],   s0,0,0,0);\
      s1 = __builtin_amdgcn_mfma_f32_32x32x16_bf16(a1, xb[2*ks2+1], s1,0,0,0);\
    }                                                                         \
    __builtin_amdgcn_s_setprio(0);                                            \
    bf16x8 pa[2];                                                             \
    _Pragma("unroll")                                                         \
    for (int ks = 0; ks < 2; ++ks) {                                          \
      const int b0 = ks * 8;                                                  \
      const float e0 = exp2f((s0[b0+0] + s1[b0+0]) * myscale);                \
      const float e1 = exp2f((s0[b0+1] + s1[b0+1]) * myscale);                \
      const float e2 = exp2f((s0[b0+2] + s1[b0+2]) * myscale);                \
      const float e3 = exp2f((s0[b0+3] + s1[b0+3]) * myscale);                \
      const float e4 = exp2f((s0[b0+4] + s1[b0+4]) * myscale);                \
      const float e5 = exp2f((s0[b0+5] + s1[b0+5]) * myscale);                \
      const float e6 = exp2f((s0[b0+6] + s1[b0+6]) * myscale);                \
      const float e7 = exp2f((s0[b0+7] + s1[b0+7]) * myscale);                \
      den += ((e0 + e1) + (e2 + e3)) + ((e4 + e5) + (e6 + e7));               \
      uint_t w0, w1, w2, w3;                                                  \
      asm("v_cvt_pk_bf16_f32 %0, %1, %2" : "=v"(w0) : "v"(e0), "v"(e1));      \
      asm("v_cvt_pk_bf16_f32 %0, %1, %2" : "=v"(w1) : "v"(e2), "v"(e3));      \
      asm("v_cvt_pk_bf16_f32 %0, %1, %2" : "=v"(w2) : "v"(e4), "v"(e5));      \
      asm("v_cvt_pk_bf16_f32 %0, %1, %2" : "=v"(w3) : "v"(e6), "v"(e7));      \
      asm("v_permlane32_swap_b32 %0, %1" : "+v"(w0), "+v"(w2));               \
      asm("v_permlane32_swap_b32 %0, %1" : "+v"(w1), "+v"(w3));               \
      uint4 u = {w0, w1, w2, w3};                                             \
      pa[ks] = __builtin_bit_cast(bf16x8, u);                                 \
    }                                                                         \
    __builtin_amdgcn_s_setprio(1);                                            \
    _Pragma("unroll")                                                         \
    for (int ks = 0; ks < 2; ++ks) {                                          \
      _Pragma("unroll")                                                       \
      for (int d0 = 0; d0 < 8; ++d0) {                                        \
        bf16x8 vf = *(const bf16x8*)(ldsb + (IMM) + 16384 + ks * 1024         \
                                     + d0 * 2048);                            \
        o8[d0] = __builtin_amdgcn_mfma_f32_32x32x16_bf16(pa[ks], vf,          \
                                                         o8[d0], 0,0,0);      \
      }                                                                       \
    }                                                                         \
    __builtin_amdgcn_s_setprio(0);                                            \
  } while (0)

  #pragma unroll 1
  for (int tt = 0; tt < 16; ++tt) {
    const int te = tt * 2;
    // even tile: buf0 (imm 0); prefetch te+1 -> buf1
    stage(te + 1, 1);
    TILE_BODY(0);
    __syncthreads();
    // odd tile: buf1 (imm 32768); prefetch te+2 -> buf0 (unless last)
    if (te + 1 < 31) stage(te + 2, 0);
    TILE_BODY(32768);
    __syncthreads();
  }
#undef TILE_BODY

  // ---- denominators: lane covers hi-half mems of x-row col
  den += __shfl_xor(den, 32);
  const float rden = 1.0f / den;
  float rdv[16];
  #pragma unroll
  for (int r = 0; r < 16; ++r)
    rdv[r] = __shfl(rden, (r & 3) + 8 * (r >> 2) + 4 * hi);

  // ---- normalize + store: row = crow(r,hi), d = d0*32+col (128B segments)
  float* op = out + (size_t)row0 * HIDDEN;
  #pragma unroll
  for (int d0 = 0; d0 < 8; ++d0) {
    #pragma unroll
    for (int r = 0; r < 16; ++r) {
      const int rw = (r & 3) + 8 * (r >> 2) + 4 * hi;
      op[(size_t)rw * HIDDEN + d0 * 32 + col] = o8[d0][r] * rdv[r];
    }
  }
}

extern "C" void kernel_launch(void* const* d_in, const int* in_sizes, int n_in,
                              void* d_out, int out_size, void* d_ws, size_t ws_size,
                              hipStream_t stream) {
  const float* x   = (const float*)d_in[0];
  const float* mem = (const float*)d_in[1];
  float* out = (float*)d_out;
  const int N = in_sizes[0] / HIDDEN;          // 131072

  ushort_t* wsm = (ushort_t*)d_ws;             // 512 KB (QK fragment image)
  ushort_t* wsv = wsm + NMEM * HIDDEN;         // 512 KB (PV fragment image)

  prep_kernel<<<NMEM, HIDDEN, 0, stream>>>(mem, wsm, wsv);
  mem_kernel<<<N / 128, 256, 0, stream>>>(x, wsm, wsv, out);
}